// Round 7
// baseline (150.602 us; speedup 1.0000x reference)
//
#include <hip/hip_runtime.h>
#include <stdint.h>

typedef __attribute__((ext_vector_type(8))) __bf16 bf16x8;
typedef __attribute__((ext_vector_type(16))) float f32x16;
typedef __attribute__((ext_vector_type(4))) unsigned int u32x4;
typedef __attribute__((ext_vector_type(4))) float f32x4;
typedef unsigned int u32;
typedef unsigned short u16;

#define THETA 0.7f

__host__ __device__ constexpr float pht_val(int q) {
  return (q == 12) ? (-4.0f + 1e-6f)
       : (q == 7 || q == 11 || q == 13 || q == 17) ? (1.0f + 1e-6f)
       : 1e-6f;
}

__device__ __forceinline__ u16 f2bf(float v) {
  u32 u = __builtin_bit_cast(u32, v);
  return (u16)((u + 0x7fffu + ((u >> 16) & 1u)) >> 16);
}

// ---------------- kernel 1: build K_eff, packed as MFMA A-fragments -------
__global__ __launch_bounds__(256) void k_prep(const float* __restrict__ wgt,
                                              const float* __restrict__ alpha,
                                              u16* __restrict__ apack) {
  int t = blockIdx.x * 256 + threadIdx.x;   // 4096 threads: (o, ci)
  int o = t >> 6, ci = t & 63;
  const float* wp = wgt + ((size_t)(o * 64 + ci)) * 25;
  float wv[25], sumw = 0.f;
#pragma unroll
  for (int p = 0; p < 25; ++p) { wv[p] = wp[p]; sumw += wv[p]; }
  float keff[25];
#pragma unroll
  for (int p = 0; p < 25; ++p) keff[p] = pht_val(p) * wv[p];  // a=0 (identity)
  constexpr int TP[33] = {0,1,2,3,4,6,7,9,12,13,  0,1,2,3,4,  0, 0, 0,
                          0,5,10,15,20,  0,5,6,10,11,12,15,17,20,21};
  constexpr int TQ[33] = {5,6,12,17,23,10,16,22,20,21,  0,5,10,15,20,  5, 0, 5,
                          0,6,7,8,9,  5,6,2,12,8,4,17,9,23,14};
#pragma unroll
  for (int e = 0; e < 33; ++e) keff[TP[e]] += pht_val(TQ[e]) * wv[TQ[e]];

  float al = alpha[0];
  int kc = ci >> 4, oh = o >> 5;
  int lane = ((ci >> 3) & 1) * 32 + (o & 31);   // A-frag: lane=(k/8)*32+m
#pragma unroll
  for (int p = 0; p < 25; ++p) {
    float v = al * (keff[p] * 0.125f);
    if (p == 12) v -= THETA * sumw;             // fold 1x1 branch into center
    size_t idx = ((((size_t)p * 4 + kc) * 2 + oh) * 64 + lane) * 8 + (ci & 7);
    apack[idx] = f2bf(v);
  }
}

// ---------------- kernel 2: x (NCHW fp32) -> X_t[n][y][px][i] bf16 --------
__global__ __launch_bounds__(256) void k_xcast(const float* __restrict__ x,
                                               u16* __restrict__ xt) {
  __shared__ u16 lt[64][130];
  int bid = blockIdx.x;                       // n*128 + y
  int n = bid >> 7, y = bid & 127;
  const float* xb = x + (size_t)n * 64 * 16384 + (size_t)y * 128;
  int t = threadIdx.x;
#pragma unroll
  for (int it = 0; it < 8; ++it) {            // float4 reads
    int idx = it * 256 + t;
    int i = idx >> 5, p4 = (idx & 31) * 4;
    f32x4 v = *(const f32x4*)(xb + (size_t)i * 16384 + p4);
    lt[i][p4 + 0] = f2bf(v.x); lt[i][p4 + 1] = f2bf(v.y);
    lt[i][p4 + 2] = f2bf(v.z); lt[i][p4 + 3] = f2bf(v.w);
  }
  __syncthreads();
  u32* xtb = (u32*)(xt + (size_t)(n * 128 + y) * 8192);
#pragma unroll
  for (int it = 0; it < 16; ++it) {           // u32 writes (2 i per lane)
    int idx = it * 256 + t;
    int px = idx >> 5, i2 = idx & 31;
    u32 w = (u32)lt[2 * i2][px] | ((u32)lt[2 * i2 + 1][px] << 16);
    xtb[(size_t)px * 32 + i2] = w;
  }
}

// ---------------- kernel 3: conv via 32x32x16 bf16 MFMA -------------------
// R6 geometry (4 rows x 64 px x 64 o, 72 KB LDS, 2 blocks/CU); compute
// restructured kc-OUTER: per kc, all 25 A-taps batch-loaded into af[25]
// (kc=0 issued before the barrier, hiding under the stage drain), then
// dx-inner: 8 ds_read_b128 + 20 MFMA. Collapses 20 scattered 5-load L2
// stalls per block into 4 batched ones.
#define ROWB 9216

__global__ __launch_bounds__(256, 2) void k_conv(const u16* __restrict__ xt,
                                                 const u32x4* __restrict__ apv,
                                                 float* __restrict__ out) {
  __shared__ char tile[8 * ROWB];             // 73728 B
  int bid = blockIdx.x;
  int lg = (bid & 7) * 256 + (bid >> 3);      // XCD swizzle (2048%8==0)
  int ph = lg & 1, yt = (lg >> 1) & 31, n = lg >> 6;
  int y0 = yt * 4, px0 = ph * 64;
  int tid = threadIdx.x;
  int l = tid & 63, wv = tid >> 6;            // 4 waves

  // ---- stage: wave wv stages tile rows 2wv, 2wv+1 (pre-swizzled source) ----
#pragma unroll
  for (int rr = 0; rr < 2; ++rr) {
    int r = 2 * wv + rr;
    int sy = y0 + r - 2;
    char* rowbase = tile + r * ROWB;
    if ((unsigned)sy < 128u) {
      // row byte base shifted so tile col c holds src px = px0 + c - 2
      const char* xrow = (const char*)xt + ((size_t)(n * 128 + sy) * 16384)
                         + (ptrdiff_t)(px0 - 2) * 128;
      int g = l & 7;
#pragma unroll
      for (int it = 0; it < 9; ++it) {        // 576 granule slots >= 544+pad
        int gi = it * 64 + l;
        int c = gi >> 3;
        bool valid = ((unsigned)(px0 + c - 2) < 128u) && (c < 68);
        if (valid) {
          const char* src = xrow + c * 128 + ((g ^ (c & 7)) << 4);
          __builtin_amdgcn_global_load_lds(
              (const __attribute__((address_space(1))) u32*)src,
              (__attribute__((address_space(3))) u32*)(rowbase + it * 1024),
              16, 0, 0);                      // HW adds lane*16
        } else {
          u32x4 z = {0u, 0u, 0u, 0u};
          *(u32x4*)(rowbase + it * 1024 + l * 16) = z;
        }
      }
    } else {                                  // out-of-image row -> zeros
      u32x4 z = {0u, 0u, 0u, 0u};
#pragma unroll
      for (int it = 0; it < 9; ++it)
        *(u32x4*)(rowbase + it * 1024 + l * 16) = z;
    }
  }

  // ---- compute: wave = (oh = o-half, q32 = px quarter), all 4 rows ----
  int oh = wv >> 1, q32 = wv & 1;
  int l31 = l & 31, lhi = l >> 5;
  const u32x4* apb = apv + (size_t)(oh * 64 + l);
  const char* pcol = tile + (q32 * 32 + l31) * 128;

  u32x4 af[25];
#pragma unroll
  for (int p = 0; p < 25; ++p) af[p] = apb[(size_t)p * 512];  // kc=0 batch,
                                                              // pre-barrier
  __syncthreads();

  f32x16 a0 = 0, a1 = 0, a2 = 0, a3 = 0;      // acc[row]

#pragma unroll
  for (int kc = 0; kc < 4; ++kc) {
#pragma unroll
    for (int dx = 0; dx < 5; ++dx) {
      int c7 = (l31 + dx) & 7;                // q32*32 doesn't change &7
      const char* pb = pcol + dx * 128;
      int gx = ((kc * 2 + lhi) ^ c7) << 4;    // swizzled granule offset
      u32x4 br[8];
#pragma unroll
      for (int j = 0; j < 8; ++j) br[j] = *(const u32x4*)(pb + j * ROWB + gx);
#pragma unroll
      for (int dy = 0; dy < 5; ++dy) {
        bf16x8 A = __builtin_bit_cast(bf16x8, af[dy * 5 + dx]);
        a0 = __builtin_amdgcn_mfma_f32_32x32x16_bf16(A, __builtin_bit_cast(bf16x8, br[dy]),     a0, 0, 0, 0);
        a1 = __builtin_amdgcn_mfma_f32_32x32x16_bf16(A, __builtin_bit_cast(bf16x8, br[dy + 1]), a1, 0, 0, 0);
        a2 = __builtin_amdgcn_mfma_f32_32x32x16_bf16(A, __builtin_bit_cast(bf16x8, br[dy + 2]), a2, 0, 0, 0);
        a3 = __builtin_amdgcn_mfma_f32_32x32x16_bf16(A, __builtin_bit_cast(bf16x8, br[dy + 3]), a3, 0, 0, 0);
      }
    }
    if (kc < 3) {                             // next kc's A batch (WAR-ordered
#pragma unroll                                // after last use; ds of next kc
      for (int p = 0; p < 25; ++p)            // fills the latency)
        af[p] = apb[(size_t)p * 512 + (kc + 1) * 128];
    }
  }

  // ---- epilogue: C/D layout col=lane&31, row=(rg&3)+8*(rg>>2)+4*(lane>>5)
  float* ob = out + ((size_t)(n * 64 + oh * 32) * 128 + y0) * 128
              + px0 + q32 * 32 + l31;
#pragma unroll
  for (int rg = 0; rg < 16; ++rg) {
    int orow = (rg & 3) + 8 * (rg >> 2) + 4 * lhi;
    float* obr = ob + (size_t)orow * 16384;
    obr[0]   = a0[rg];
    obr[128] = a1[rg];
    obr[256] = a2[rg];
    obr[384] = a3[rg];
  }
}

extern "C" void kernel_launch(void* const* d_in, const int* in_sizes, int n_in,
                              void* d_out, int out_size, void* d_ws, size_t ws_size,
                              hipStream_t stream) {
  const float* x     = (const float*)d_in[0];   // (32,64,128,128) fp32
  const float* wgt   = (const float*)d_in[1];   // (64,64,5,5) fp32
  const float* alpha = (const float*)d_in[2];   // (1,) fp32
  float* out = (float*)d_out;

  u16* apack = (u16*)d_ws;                                  // 204800 B
  u16* xt    = (u16*)((char*)d_ws + (1 << 20));             // 64 MiB

  k_prep <<<16,   256, 0, stream>>>(wgt, alpha, apack);
  k_xcast<<<4096, 256, 0, stream>>>(x, xt);
  k_conv <<<2048, 256, 0, stream>>>(xt, (const u32x4*)apack, out);
}